// Round 6
// baseline (50.688 us; speedup 1.0000x reference)
//
#include <hip/hip_runtime.h>

// LocalizationAttacks: per-segment (1600 samples) attack decision applied
// elementwise to B x T audio. Outputs (concatenated flat planes):
//   attacked        = c==0 ? watermarked : (c==1 ? original : 0)
//   ground_truth    = c==0 ? 1 : 0
//   update_original = c==2 ? 0 : original
// where c = 0 (not attacked), 1 (attacked & revert), 2 (attacked & zeroed).
//
// Fused single kernel; each 256-thread block processes 512 consecutive
// float4s (2048 samples, 2x unroll per thread) -> spans at most 3 segments.
// Wave 0 computes the (up to) 3 segment codes via __ballot membership on
// seg_starts, broadcast through LDS. 2x unroll halves the per-block
// prologue count and doubles per-thread memory-level parallelism.

#define SEGLEN 1600
#define SEG4   (SEGLEN / 4)   // 400 float4s per segment
#define UNROLL 2

__global__ void attack_fused_kernel(const float4* __restrict__ orig,
                                    const float4* __restrict__ wm,
                                    const int*    __restrict__ seg_starts,
                                    const int*    __restrict__ rflags,
                                    float4*       __restrict__ out,
                                    int N4,          // T/4 float4s per batch row
                                    int S,
                                    int S_mod,
                                    long long BT4)   // B*N4 = output plane stride
{
    const int b = blockIdx.y;

    // --- segment codes for this block's window (wave 0, LDS broadcast) ---
    __shared__ int scode[3];
    const int blk_begin = blockIdx.x * (blockDim.x * UNROLL);      // float4 idx
    const int blk_last  = min(blk_begin + (int)(blockDim.x * UNROLL) - 1, N4 - 1);
    const int s0 = blk_begin / SEG4;     // const divide -> magic mul
    const int sl = blk_last  / SEG4;     // s0 .. s0+2

    if (threadIdx.x < 64) {
        const int lane = threadIdx.x;
        bool hit0 = false, hit1 = false, hit2 = false;
        for (int i = lane; i < S_mod; i += 64) {
            const int sv = seg_starts[b * S_mod + i];   // 240 B, L2-broadcast
            hit0 |= (sv == s0);
            hit1 |= (sv == s0 + 1);
            hit2 |= (sv == s0 + 2);
        }
        const unsigned long long m0 = __ballot(hit0);
        const unsigned long long m1 = __ballot(hit1);
        const unsigned long long m2 = __ballot(hit2);
        if (lane == 0) {
            scode[0] = m0 ? (rflags[b * S + s0] ? 1 : 2) : 0;
            scode[1] = (s0 + 1 <= sl) ? (m1 ? (rflags[b * S + s0 + 1] ? 1 : 2) : 0) : 0;
            scode[2] = (s0 + 2 <= sl) ? (m2 ? (rflags[b * S + s0 + 2] ? 1 : 2) : 0) : 0;
        }
    }
    __syncthreads();

    // --- elementwise float4 pass, 2 float4s per thread ---
    const long long rowbase = (long long)b * N4;
    const float4 z    = make_float4(0.f, 0.f, 0.f, 0.f);
    const float4 ones = make_float4(1.f, 1.f, 1.f, 1.f);

    #pragma unroll
    for (int u = 0; u < UNROLL; ++u) {
        const int i4 = blk_begin + u * blockDim.x + threadIdx.x;
        if (i4 >= N4) break;

        const int c = scode[i4 / SEG4 - s0];
        const long long base = rowbase + i4;

        float4 att, gt, up;
        if (c == 0) {                 // not attacked: need both inputs
            att = wm[base];
            up  = orig[base];
            gt  = ones;
        } else if (c == 1) {          // attacked & reverted: only original
            const float4 o = orig[base];
            att = o; gt = z; up = o;
        } else {                      // attacked & zeroed: no input needed
            att = z; gt = z; up = z;
        }

        out[base]           = att;   // attacked
        out[base + BT4]     = gt;    // ground_truth
        out[base + 2 * BT4] = up;    // update_original
    }
}

extern "C" void kernel_launch(void* const* d_in, const int* in_sizes, int n_in,
                              void* d_out, int out_size, void* d_ws, size_t ws_size,
                              hipStream_t stream) {
    const float* orig       = (const float*)d_in[0];
    const float* wm         = (const float*)d_in[1];
    const int*   seg_starts = (const int*)d_in[2];
    const int*   rflags     = (const int*)d_in[3];
    float*       out        = (float*)d_out;

    // Shapes per the reference: original=[B,1,T] with T=480000 (30s @ 16kHz),
    // S = T/SEGLEN = 300, seg_starts=[B,S_mod], revert_flags=[B,S].
    const int Tn    = 480000;
    const int Bn    = in_sizes[0] / Tn;
    const int Sn    = Tn / SEGLEN;               // 300
    const int S_mod = in_sizes[2] / Bn;          // 60

    const int N4 = Tn / 4;                       // 120000
    const long long BT4 = (long long)Bn * N4;    // 3,840,000
    const int per_block = 256 * UNROLL;          // 512 float4s
    dim3 grid((N4 + per_block - 1) / per_block, Bn);
    attack_fused_kernel<<<grid, 256, 0, stream>>>(
        (const float4*)orig, (const float4*)wm, seg_starts, rflags,
        (float4*)out, N4, Sn, S_mod, BT4);
}

// Round 7
// 48.870 us; speedup vs baseline: 1.0372x; 1.0372x over previous
//
#include <hip/hip_runtime.h>

// LocalizationAttacks: per-segment (1600 samples) attack decision applied
// elementwise to B x T audio. Outputs (concatenated flat planes):
//   attacked        = c==0 ? watermarked : (c==1 ? original : 0)
//   ground_truth    = c==0 ? 1 : 0
//   update_original = c==2 ? 0 : original
// where c = 0 (not attacked), 1 (attacked & revert), 2 (attacked & zeroed).
//
// Single fused kernel (round-5 configuration — best measured: 49.1 us,
// ~94% of the 6.3 TB/s copy ceiling for the 290 MB of traffic).
// Each block spans at most 2 segments (256 float4 = 1024 samples < 1600),
// so wave 0 computes the 2 segment codes via __ballot membership on
// seg_starts, broadcast through LDS. Conditional loads skip wm fetch for
// attacked segments (20%) and orig fetch for zeroed segments (~10%).
//
// Round-6 post-mortem (kept for the record): 2x unroll REGRESSED
// (49.1 -> 50.7 us) — prologue cost was already hidden; fewer blocks
// traded away latency-hiding TLP. Do not re-try.

#define SEGLEN 1600
#define SEG4   (SEGLEN / 4)   // 400 float4s per segment

__global__ void attack_fused_kernel(const float4* __restrict__ orig,
                                    const float4* __restrict__ wm,
                                    const int*    __restrict__ seg_starts,
                                    const int*    __restrict__ rflags,
                                    float4*       __restrict__ out,
                                    int N4,          // T/4 float4s per batch row
                                    int S,
                                    int S_mod,
                                    long long BT4)   // B*N4 = output plane stride
{
    const int b = blockIdx.y;

    // --- segment codes for this block (wave 0 computes, LDS broadcast) ---
    __shared__ int scode[2];
    const int blk_begin = blockIdx.x * blockDim.x;                 // float4 idx
    const int blk_last  = min(blk_begin + (int)blockDim.x - 1, N4 - 1);
    const int s0 = blk_begin / SEG4;     // const divide -> magic mul
    const int s1 = blk_last  / SEG4;     // s1 == s0 or s0+1

    if (threadIdx.x < 64) {
        const int lane = threadIdx.x;
        bool hit0 = false, hit1 = false;
        for (int i = lane; i < S_mod; i += 64) {
            const int sv = seg_starts[b * S_mod + i];   // 240 B, L2-broadcast
            hit0 |= (sv == s0);
            hit1 |= (sv == s1);
        }
        const unsigned long long m0 = __ballot(hit0);
        const unsigned long long m1 = __ballot(hit1);
        if (lane == 0) {
            scode[0] = m0 ? (rflags[b * S + s0] ? 1 : 2) : 0;
            scode[1] = m1 ? (rflags[b * S + s1] ? 1 : 2) : 0;
        }
    }
    __syncthreads();

    // --- elementwise float4 pass ---
    const int i4 = blk_begin + threadIdx.x;
    if (i4 >= N4) return;

    const int s = i4 / SEG4;
    const int c = scode[s - s0];

    const long long base = (long long)b * N4 + i4;
    const float4 z    = make_float4(0.f, 0.f, 0.f, 0.f);
    const float4 ones = make_float4(1.f, 1.f, 1.f, 1.f);

    float4 att, gt, up;
    if (c == 0) {                 // not attacked: need both inputs
        att = wm[base];
        up  = orig[base];
        gt  = ones;
    } else if (c == 1) {          // attacked & reverted: only original
        const float4 o = orig[base];
        att = o; gt = z; up = o;
    } else {                      // attacked & zeroed: no input needed
        att = z; gt = z; up = z;
    }

    out[base]           = att;   // attacked
    out[base + BT4]     = gt;    // ground_truth
    out[base + 2 * BT4] = up;    // update_original
}

extern "C" void kernel_launch(void* const* d_in, const int* in_sizes, int n_in,
                              void* d_out, int out_size, void* d_ws, size_t ws_size,
                              hipStream_t stream) {
    const float* orig       = (const float*)d_in[0];
    const float* wm         = (const float*)d_in[1];
    const int*   seg_starts = (const int*)d_in[2];
    const int*   rflags     = (const int*)d_in[3];
    float*       out        = (float*)d_out;

    // Shapes per the reference: original=[B,1,T] with T=480000 (30s @ 16kHz),
    // S = T/SEGLEN = 300, seg_starts=[B,S_mod], revert_flags=[B,S].
    const int Tn    = 480000;
    const int Bn    = in_sizes[0] / Tn;
    const int Sn    = Tn / SEGLEN;               // 300
    const int S_mod = in_sizes[2] / Bn;          // 60

    const int N4 = Tn / 4;                       // 120000
    const long long BT4 = (long long)Bn * N4;    // 3,840,000
    dim3 grid((N4 + 255) / 256, Bn);
    attack_fused_kernel<<<grid, 256, 0, stream>>>(
        (const float4*)orig, (const float4*)wm, seg_starts, rflags,
        (float4*)out, N4, Sn, S_mod, BT4);
}